// Round 6
// baseline (353.782 us; speedup 1.0000x reference)
//
#include <hip/hip_runtime.h>
#include <hip/hip_bf16.h>

// FourierKANLayer: out[n,o] = bias[o] + sum_{i,b} coeffs[o,i,b] * basis[n,i,b]
// basis = [1, sin(m*pi*x) m=1..32, cos(m*pi*x) m=1..32] per (n,i).
//
// R7: K-SPLIT for occupancy. R6 post-mortem showed the three pipe loads
// (MFMA 13.7us, LDS-read 20.6us, VALU ~12us) running serially: with 32
// rows/wave the kernel is pinned at 8 waves/CU (2/SIMD, barrier-lockstep),
// so no cross-wave overlap. Fix: each 32-row tile is computed by TWO waves,
// one per i-half (i<32 / i>=32), partial sums reduced through LDS at the
// end.  4096 waves = 16/CU = 4/SIMD; per-wave Chebyshev state halves
// (80 floats) so 4 waves/SIMD fits at <=128 VGPR.
// Totals unchanged (same MFMA count, same LDS bytes, same staging);
// only the distribution changes -> wave-level overlap (m114 mechanism).
// Numerics: identical ops to R1 (scalar casts, same fmaf recurrence);
// only the final fp32 accumulation order changes.

typedef __bf16 bf16x8 __attribute__((ext_vector_type(8)));
typedef float  f32x4  __attribute__((ext_vector_type(4)));
typedef float  f32x16 __attribute__((ext_vector_type(16)));

#define PI_F 3.14159265358979323846f

// ---------------------------------------------------------------------------
// Repack coeffs [64][64][65] fp32 -> Bp bf16 in 32x32x16 B-fragment order.
// frag = (m*8 + kc)*2 + cc   (m=mode-1 in [0,32), kc in [0,8), cc in [0,2))
// lane: col o = cc*32 + (lane&31), kq = lane>>5
// t in [0,8): i = kc*8 + kq*4 + (t>>1); b = (t&1) ? 33+m : 1+m
// Bp[frag*512 + lane*8 + t] = coeffs[o][i][b]
// bias2[o] = bias[o] + sum_i coeffs[o][i][0]  (block 0, threads 0..63).
// ---------------------------------------------------------------------------
__global__ __launch_bounds__(256) void fkan_repack(
    const float* __restrict__ coeffs, const float* __restrict__ bias,
    __bf16* __restrict__ Bp, float* __restrict__ bias2) {
  int gid  = blockIdx.x * 256 + threadIdx.x;   // 0 .. 32767
  int lane = gid & 63;
  int frag = gid >> 6;                          // 0..511
  int m  = frag >> 4;
  int kc = (frag >> 1) & 7;
  int cc = frag & 1;
  int o  = cc * 32 + (lane & 31);
  int kq = lane >> 5;

  bf16x8 v;
  #pragma unroll
  for (int t = 0; t < 8; ++t) {
    int i = kc * 8 + kq * 4 + (t >> 1);
    int b = (t & 1) ? (33 + m) : (1 + m);
    v[t] = (__bf16)coeffs[(o * 64 + i) * 65 + b];
  }
  *(bf16x8*)(Bp + (size_t)frag * 512 + lane * 8) = v;

  if (blockIdx.x == 0 && threadIdx.x < 64) {
    int oo = threadIdx.x;
    float s = bias[oo];
    #pragma unroll 4
    for (int ii = 0; ii < 64; ++ii) s += coeffs[(oo * 64 + ii) * 65 + 0];
    bias2[oo] = s;
  }
}

// ---------------------------------------------------------------------------
// Staging: 512 threads DMA one 16 KB mode-tile (2 x 16B per thread).
// LDS dest = wave-uniform base + lane*16 (tid*16 decomposes correctly).
// ---------------------------------------------------------------------------
__device__ __forceinline__ void stage_mode(const __bf16* __restrict__ Bp,
                                           __bf16* dst, int m, int tid) {
  const char* g = (const char*)Bp + (size_t)m * 16384 + tid * 16;
  char* l = (char*)dst + tid * 16;
  __builtin_amdgcn_global_load_lds(
      (const __attribute__((address_space(1))) void*)g,
      (__attribute__((address_space(3))) void*)l, 16, 0, 0);
  __builtin_amdgcn_global_load_lds(
      (const __attribute__((address_space(1))) void*)(g + 8192),
      (__attribute__((address_space(3))) void*)(l + 8192), 16, 0, 0);
}

// ---------------------------------------------------------------------------
// One mode, one i-half: 4 A-frags (kc = 4h+kcr), 8 ds_read_b128, 8 MFMA,
// then Chebyshev advance of the 16 instances (sN/cN <- T*sA/cA - sN/cN).
// Plain HIP ds_reads (compiler emits ds_read_b128 + fine lgkmcnt, m97).
// ---------------------------------------------------------------------------
__device__ __forceinline__ void mode_compute(const __bf16* buf, int lane,
    int h, const float* T, const float* sA, const float* cA,
    float* sN, float* cN, f32x16* acc) {
  #pragma unroll
  for (int kcr = 0; kcr < 4; ++kcr) {
    bf16x8 af;
    #pragma unroll
    for (int e = 0; e < 4; ++e) {
      af[2 * e]     = (__bf16)sA[kcr * 4 + e];
      af[2 * e + 1] = (__bf16)cA[kcr * 4 + e];
    }
    int kc = 4 * h + kcr;
    #pragma unroll
    for (int c2 = 0; c2 < 2; ++c2) {
      bf16x8 bfv = *(const bf16x8*)(buf + (kc * 2 + c2) * 512 + lane * 8);
      acc[c2] = __builtin_amdgcn_mfma_f32_32x32x16_bf16(af, bfv, acc[c2],
                                                        0, 0, 0);
    }
  }
  #pragma unroll
  for (int p = 0; p < 16; ++p) {
    sN[p] = fmaf(T[p], sA[p], -sN[p]);
    cN[p] = fmaf(T[p], cA[p], -cN[p]);
  }
}

// ---------------------------------------------------------------------------
// Main kernel: 512 threads = 8 waves = 4 row-tiles x 2 i-halves;
// block = 128 rows x 64 cols; grid = 512 (2 blocks/CU, 16 waves/CU).
// wave w: row-tile rt = w>>1 (rows blk*128+rt*32..+32), i-half h = w&1
// (i in [32h, 32h+32)).  Per mode each wave: 8 MFMA over its K-half.
// Epilogue: h=1 waves write partial acc to LDS (stride-64 b32, conflict-
// free), barrier, h=0 waves add + store.
// ---------------------------------------------------------------------------
__global__ __launch_bounds__(512, 4) void fkan_main(
    const float* __restrict__ x, const __bf16* __restrict__ Bp,
    const float* __restrict__ bias2, float* __restrict__ out) {
  __shared__ __bf16 Bs[2][8192];   // 2 x 16 KB double buffer; reused as
                                   // float[8192] (32 KB) for the reduction

  int tid  = threadIdx.x;
  int wave = tid >> 6;             // 0..7
  int rt   = wave >> 1;            // row-tile 0..3
  int h    = wave & 1;             // i-half
  int lane = tid & 63;
  int kq   = lane >> 5;
  int cl   = lane & 31;
  int row  = blockIdx.x * 128 + rt * 32 + cl;

  // --- init: sincos(pi*x) for the lane's 16 (row,i) instances -------------
  // p = kcr*4 + e  ->  i = 32h + kcr*8 + kq*4 + e
  float T[16], sp[16], cp[16], sc[16], cc_[16];
  const float* xrow = x + (size_t)row * 64 + h * 32 + kq * 4;
  #pragma unroll
  for (int kcr = 0; kcr < 4; ++kcr) {
    f32x4 v = *(const f32x4*)(xrow + kcr * 8);
    #pragma unroll
    for (int e = 0; e < 4; ++e) {
      int p = kcr * 4 + e;
      float ss, cs;
      __sincosf(PI_F * v[e], &ss, &cs);
      T[p] = 2.0f * cs;          // Chebyshev multiplier
      sc[p] = ss;  cc_[p] = cs;  // current  = freq 1
      sp[p] = 0.f; cp[p] = 1.f;  // previous = freq 0
    }
  }

  f32x16 acc[2];
  #pragma unroll
  for (int c2 = 0; c2 < 2; ++c2)
    #pragma unroll
    for (int r = 0; r < 16; ++r) acc[c2][r] = 0.f;

  // --- prologue: stage mode 0 ---------------------------------------------
  stage_mode(Bp, &Bs[0][0], 0, tid);
  __syncthreads();

  // --- main loop: modes 0..29 (R1's verified skeleton) --------------------
  #pragma unroll 1
  for (int m = 0; m < 30; m += 2) {
    stage_mode(Bp, &Bs[1][0], m + 1, tid);
    mode_compute(&Bs[0][0], lane, h, T, sc, cc_, sp, cp, acc);   // mode m
    __syncthreads();

    stage_mode(Bp, &Bs[0][0], m + 2, tid);
    mode_compute(&Bs[1][0], lane, h, T, sp, cp, sc, cc_, acc);   // mode m+1
    __syncthreads();
  }

  // --- tail: modes 30, 31 --------------------------------------------------
  stage_mode(Bp, &Bs[1][0], 31, tid);
  mode_compute(&Bs[0][0], lane, h, T, sc, cc_, sp, cp, acc);     // mode 30
  __syncthreads();
  mode_compute(&Bs[1][0], lane, h, T, sp, cp, sc, cc_, acc);     // mode 31
  __syncthreads();   // all B-tile reads retired; Bs reusable for reduction

  // --- cross-half reduction through LDS -----------------------------------
  // layout: red[rt*2048 + r*64 + lane], r in [0,32): bank = lane%32 ->
  // 2 lanes/bank (free).  8192 floats = 32 KB = exactly Bs.
  float* red = (float*)&Bs[0][0];
  if (h == 1) {
    #pragma unroll
    for (int r = 0; r < 32; ++r)
      red[rt * 2048 + r * 64 + lane] = acc[r >> 4][r & 15];
  }
  __syncthreads();

  if (h == 0) {
    #pragma unroll
    for (int r = 0; r < 32; ++r)
      acc[r >> 4][r & 15] += red[rt * 2048 + r * 64 + lane];

    // epilogue: C/D layout col=lane&31, row=(r&3)+8*(r>>2)+4*(lane>>5)
    float* orow = out + (size_t)(blockIdx.x * 128 + rt * 32) * 64;
    #pragma unroll
    for (int c2 = 0; c2 < 2; ++c2) {
      float b2 = bias2[c2 * 32 + cl];
      #pragma unroll
      for (int r = 0; r < 16; ++r) {
        int ro = (r & 3) + 8 * (r >> 2) + 4 * kq;
        orow[(size_t)ro * 64 + c2 * 32 + cl] = acc[c2][r] + b2;
      }
    }
  }
}

extern "C" void kernel_launch(void* const* d_in, const int* in_sizes, int n_in,
                              void* d_out, int out_size, void* d_ws, size_t ws_size,
                              hipStream_t stream) {
  const float* x      = (const float*)d_in[0];   // [65536, 64]
  const float* coeffs = (const float*)d_in[1];   // [64, 64, 65]
  const float* bias   = (const float*)d_in[2];   // [64]
  float* out = (float*)d_out;

  __bf16* Bp   = (__bf16*)d_ws;                  // 512 KB
  float* bias2 = (float*)((char*)d_ws + 512 * 1024);

  int n_rows = in_sizes[0] / 64;                 // 65536

  fkan_repack<<<128, 256, 0, stream>>>(coeffs, bias, Bp, bias2);
  fkan_main<<<n_rows / 128, 512, 0, stream>>>(x, Bp, bias2, out);
}

// Round 7
// 196.486 us; speedup vs baseline: 1.8005x; 1.8005x over previous
//
#include <hip/hip_runtime.h>
#include <hip/hip_bf16.h>

// FourierKANLayer: out[n,o] = bias[o] + sum_{i,b} coeffs[o,i,b] * basis[n,i,b]
// basis = [1, sin(m*pi*x) m=1..32, cos(m*pi*x) m=1..32] per (n,i).
//
// R8: occupancy fix done RIGHT (R7 post-mortem: __launch_bounds__(512,4)'s
// 128-unified-reg budget vs ~145-reg demand -> total spill, 1.2GB scratch).
//  - Rotation recurrence (s,c)*(c1,s1) replaces Chebyshev: 4 regs/instance
//    (s1,c1,s,c) vs 5 -> per-wave state 64 + acc 32 ~= 115 unified, FITS
//    the 128-reg budget of 4 waves/SIMD. Norm-preserving (numerically
//    gentler than Chebyshev's |T|<=2 amplification).
//  - 256-thread blocks (4 waves = 2 row-tiles x 2 K-halves, 64 rows/block),
//    LDS 32 KB -> __launch_bounds__(256,4) = 4 blocks/CU, grid 1024.
//    Each SIMD hosts 4 waves from 4 DIFFERENT blocks: no shared barrier,
//    independent streams -> MFMA/LDS/VALU pipes overlap across waves
//    (m114), instead of R6's serial per-wave sum (13.7+12+20.6 ~= 48us).
//  - Sync skeleton = R1's verified stage -> compute -> __syncthreads.
//    While one block drains its barrier, the other three compute.

typedef __bf16 bf16x8 __attribute__((ext_vector_type(8)));
typedef float  f32x4  __attribute__((ext_vector_type(4)));
typedef float  f32x16 __attribute__((ext_vector_type(16)));

#define PI_F 3.14159265358979323846f

// ---------------------------------------------------------------------------
// Repack coeffs [64][64][65] fp32 -> Bp bf16 in 32x32x16 B-fragment order.
// frag = (m*8 + kc)*2 + cc   (m=mode-1 in [0,32), kc in [0,8), cc in [0,2))
// lane: col o = cc*32 + (lane&31), kq = lane>>5
// t in [0,8): i = kc*8 + kq*4 + (t>>1); b = (t&1) ? 33+m : 1+m
// Bp[frag*512 + lane*8 + t] = coeffs[o][i][b]
// bias2[o] = bias[o] + sum_i coeffs[o][i][0]  (block 0, threads 0..63).
// ---------------------------------------------------------------------------
__global__ __launch_bounds__(256) void fkan_repack(
    const float* __restrict__ coeffs, const float* __restrict__ bias,
    __bf16* __restrict__ Bp, float* __restrict__ bias2) {
  int gid  = blockIdx.x * 256 + threadIdx.x;   // 0 .. 32767
  int lane = gid & 63;
  int frag = gid >> 6;                          // 0..511
  int m  = frag >> 4;
  int kc = (frag >> 1) & 7;
  int cc = frag & 1;
  int o  = cc * 32 + (lane & 31);
  int kq = lane >> 5;

  bf16x8 v;
  #pragma unroll
  for (int t = 0; t < 8; ++t) {
    int i = kc * 8 + kq * 4 + (t >> 1);
    int b = (t & 1) ? (33 + m) : (1 + m);
    v[t] = (__bf16)coeffs[(o * 64 + i) * 65 + b];
  }
  *(bf16x8*)(Bp + (size_t)frag * 512 + lane * 8) = v;

  if (blockIdx.x == 0 && threadIdx.x < 64) {
    int oo = threadIdx.x;
    float s = bias[oo];
    #pragma unroll 4
    for (int ii = 0; ii < 64; ++ii) s += coeffs[(oo * 64 + ii) * 65 + 0];
    bias2[oo] = s;
  }
}

// ---------------------------------------------------------------------------
// Staging: 256 threads DMA one 16 KB mode-tile (4 x 16B per thread, stride
// 4 KB).  Per chunk: LDS dest = wave-uniform base + lane*16 (HW rule).
// ---------------------------------------------------------------------------
__device__ __forceinline__ void stage_mode(const __bf16* __restrict__ Bp,
                                           __bf16* dst, int m, int tid) {
  const char* g = (const char*)Bp + (size_t)m * 16384 + tid * 16;
  char* l = (char*)dst + tid * 16;
  #pragma unroll
  for (int r = 0; r < 4; ++r) {
    __builtin_amdgcn_global_load_lds(
        (const __attribute__((address_space(1))) void*)(g + r * 4096),
        (__attribute__((address_space(3))) void*)(l + r * 4096), 16, 0, 0);
  }
}

// ---------------------------------------------------------------------------
// One mode, one i-half: 4 A-frags (kc = 4h+kcr), 8 ds_read_b128, 8 MFMA,
// then rotation advance: (s,c) <- (s*c1 + c*s1, c*c1 - s*s1).
// Packing = scalar (__bf16) casts (R1-verified numerics).
// ---------------------------------------------------------------------------
__device__ __forceinline__ void mode_compute(const __bf16* buf, int lane,
    int h, const float* s1, const float* c1, float* s, float* c,
    f32x16* acc) {
  #pragma unroll
  for (int kcr = 0; kcr < 4; ++kcr) {
    bf16x8 af;
    #pragma unroll
    for (int e = 0; e < 4; ++e) {
      af[2 * e]     = (__bf16)s[kcr * 4 + e];
      af[2 * e + 1] = (__bf16)c[kcr * 4 + e];
    }
    int kc = 4 * h + kcr;
    #pragma unroll
    for (int c2 = 0; c2 < 2; ++c2) {
      bf16x8 bfv = *(const bf16x8*)(buf + (kc * 2 + c2) * 512 + lane * 8);
      acc[c2] = __builtin_amdgcn_mfma_f32_32x32x16_bf16(af, bfv, acc[c2],
                                                        0, 0, 0);
    }
  }
  #pragma unroll
  for (int p = 0; p < 16; ++p) {
    float ns = fmaf(c[p], s1[p], s[p] * c1[p]);
    float nc = fmaf(-s[p], s1[p], c[p] * c1[p]);
    s[p] = ns;
    c[p] = nc;
  }
}

// ---------------------------------------------------------------------------
// Main kernel: 256 threads = 4 waves = 2 row-tiles x 2 i-halves;
// block = 64 rows x 64 cols; grid = 1024 (4 blocks/CU, 16 waves/CU).
// wave w: row-tile rt = w>>1 (rows blk*64+rt*32..+32), i-half h = w&1
// (i in [32h, 32h+32)).  Per mode each wave: 8 MFMA over its K-half.
// Epilogue: h=1 waves write partial acc to LDS (2 lanes/bank = free),
// barrier, h=0 waves add + store.
// ---------------------------------------------------------------------------
__global__ __launch_bounds__(256, 4) void fkan_main(
    const float* __restrict__ x, const __bf16* __restrict__ Bp,
    const float* __restrict__ bias2, float* __restrict__ out) {
  __shared__ __bf16 Bs[2][8192];   // 2 x 16 KB double buffer; Bs[0] reused
                                   // as float[4096] (16 KB) for reduction

  int tid  = threadIdx.x;
  int wave = tid >> 6;             // 0..3
  int rt   = wave >> 1;            // row-tile 0..1
  int h    = wave & 1;             // i-half
  int lane = tid & 63;
  int kq   = lane >> 5;
  int cl   = lane & 31;
  int row  = blockIdx.x * 64 + rt * 32 + cl;

  // --- init: sincos(pi*x) for the lane's 16 (row,i) instances -------------
  // p = kcr*4 + e  ->  i = 32h + kcr*8 + kq*4 + e
  float s1[16], c1[16], s[16], c[16];
  const float* xrow = x + (size_t)row * 64 + h * 32 + kq * 4;
  #pragma unroll
  for (int kcr = 0; kcr < 4; ++kcr) {
    f32x4 v = *(const f32x4*)(xrow + kcr * 8);
    #pragma unroll
    for (int e = 0; e < 4; ++e) {
      int p = kcr * 4 + e;
      float ss, cs;
      __sincosf(PI_F * v[e], &ss, &cs);
      s1[p] = ss;  c1[p] = cs;     // rotation step (static)
      s[p]  = ss;  c[p]  = cs;     // current = freq 1
    }
  }

  f32x16 acc[2];
  #pragma unroll
  for (int c2 = 0; c2 < 2; ++c2)
    #pragma unroll
    for (int r = 0; r < 16; ++r) acc[c2][r] = 0.f;

  // --- prologue: stage mode 0 ---------------------------------------------
  stage_mode(Bp, &Bs[0][0], 0, tid);
  __syncthreads();

  // --- main loop: modes 0..29 (R1's verified skeleton) --------------------
  #pragma unroll 1
  for (int m = 0; m < 30; m += 2) {
    stage_mode(Bp, &Bs[1][0], m + 1, tid);
    mode_compute(&Bs[0][0], lane, h, s1, c1, s, c, acc);   // mode m
    __syncthreads();

    stage_mode(Bp, &Bs[0][0], m + 2, tid);
    mode_compute(&Bs[1][0], lane, h, s1, c1, s, c, acc);   // mode m+1
    __syncthreads();
  }

  // --- tail: modes 30, 31 --------------------------------------------------
  stage_mode(Bp, &Bs[1][0], 31, tid);
  mode_compute(&Bs[0][0], lane, h, s1, c1, s, c, acc);     // mode 30
  __syncthreads();
  mode_compute(&Bs[1][0], lane, h, s1, c1, s, c, acc);     // mode 31
  __syncthreads();   // all B-tile reads retired; Bs[0] reusable

  // --- cross-half reduction through LDS -----------------------------------
  // red[rt*2048 + r*64 + lane]: bank = lane%32 -> 2 lanes/bank (free).
  // 2 row-tiles x 2048 floats = 16 KB = Bs[0].
  float* red = (float*)&Bs[0][0];
  if (h == 1) {
    #pragma unroll
    for (int r = 0; r < 32; ++r)
      red[rt * 2048 + r * 64 + lane] = acc[r >> 4][r & 15];
  }
  __syncthreads();

  if (h == 0) {
    #pragma unroll
    for (int r = 0; r < 32; ++r)
      acc[r >> 4][r & 15] += red[rt * 2048 + r * 64 + lane];

    // epilogue: C/D layout col=lane&31, row=(r&3)+8*(r>>2)+4*(lane>>5)
    float* orow = out + (size_t)(blockIdx.x * 64 + rt * 32) * 64;
    #pragma unroll
    for (int c2 = 0; c2 < 2; ++c2) {
      float b2 = bias2[c2 * 32 + cl];
      #pragma unroll
      for (int r = 0; r < 16; ++r) {
        int ro = (r & 3) + 8 * (r >> 2) + 4 * kq;
        orow[(size_t)ro * 64 + c2 * 32 + cl] = acc[c2][r] + b2;
      }
    }
  }
}

extern "C" void kernel_launch(void* const* d_in, const int* in_sizes, int n_in,
                              void* d_out, int out_size, void* d_ws, size_t ws_size,
                              hipStream_t stream) {
  const float* x      = (const float*)d_in[0];   // [65536, 64]
  const float* coeffs = (const float*)d_in[1];   // [64, 64, 65]
  const float* bias   = (const float*)d_in[2];   // [64]
  float* out = (float*)d_out;

  __bf16* Bp   = (__bf16*)d_ws;                  // 512 KB
  float* bias2 = (float*)((char*)d_ws + 512 * 1024);

  int n_rows = in_sizes[0] / 64;                 // 65536

  fkan_repack<<<128, 256, 0, stream>>>(coeffs, bias, Bp, bias2);
  fkan_main<<<n_rows / 64, 256, 0, stream>>>(x, Bp, bias2, out);
}

// Round 8
// 123.780 us; speedup vs baseline: 2.8582x; 1.5874x over previous
//
#include <hip/hip_runtime.h>
#include <hip/hip_bf16.h>

// FourierKANLayer: out[n,o] = bias[o] + sum_{i,b} coeffs[o,i,b] * basis[n,i,b]
// basis = [1, sin(m*pi*x) m=1..32, cos(m*pi*x) m=1..32] per (n,i).
//
// R9: STATELESS basis -> fit the 64-arch-VGPR occupancy tier.
// R7/R8 post-mortem law: occupancy tiers quantize at 64/128/256 unified
// regs/wave; asking for 4 waves/SIMD gives a 64-ARCH + 64-ACC split.
// Any recurrence state (Chebyshev 5/instance, rotation 4/instance) blows
// the 64-arch budget at 16 instances/lane -> spill -> scratch-bound.
// Fix: keep only ax = x/2 per instance (16 regs). Per mode f=m+1:
//   sin(pi*f*x) = sin_rev(f*x/2):  r = f*ax; rr = fract(r); v_sin/v_cos.
// HW trans ops (1/4 rate) cost more VALU than the recurrence, but the
// freed registers buy 4 waves/SIMD from 4 INDEPENDENT blocks -> the three
// pipes (MFMA 1033 cyc, VALU ~1540 cyc, LDS ~1000-1500 cyc per SIMD per
// mode) overlap across waves (m114) instead of serializing (R6: 48us).
// Numerics: angle err ~4e-5 rad << bf16 cast err; no error accumulation.
// Structure (staging, K-split mapping, epilogue reduction, R1 sync
// skeleton) is identical to the correctness-PASSED R8.

typedef __bf16 bf16x8 __attribute__((ext_vector_type(8)));
typedef float  f32x4  __attribute__((ext_vector_type(4)));
typedef float  f32x16 __attribute__((ext_vector_type(16)));

#define PI_F 3.14159265358979323846f

// ---------------------------------------------------------------------------
// Repack coeffs [64][64][65] fp32 -> Bp bf16 in 32x32x16 B-fragment order.
// frag = (m*8 + kc)*2 + cc   (m=mode-1 in [0,32), kc in [0,8), cc in [0,2))
// lane: col o = cc*32 + (lane&31), kq = lane>>5
// t in [0,8): i = kc*8 + kq*4 + (t>>1); b = (t&1) ? 33+m : 1+m
// Bp[frag*512 + lane*8 + t] = coeffs[o][i][b]
// bias2[o] = bias[o] + sum_i coeffs[o][i][0]  (block 0, threads 0..63).
// ---------------------------------------------------------------------------
__global__ __launch_bounds__(256) void fkan_repack(
    const float* __restrict__ coeffs, const float* __restrict__ bias,
    __bf16* __restrict__ Bp, float* __restrict__ bias2) {
  int gid  = blockIdx.x * 256 + threadIdx.x;   // 0 .. 32767
  int lane = gid & 63;
  int frag = gid >> 6;                          // 0..511
  int m  = frag >> 4;
  int kc = (frag >> 1) & 7;
  int cc = frag & 1;
  int o  = cc * 32 + (lane & 31);
  int kq = lane >> 5;

  bf16x8 v;
  #pragma unroll
  for (int t = 0; t < 8; ++t) {
    int i = kc * 8 + kq * 4 + (t >> 1);
    int b = (t & 1) ? (33 + m) : (1 + m);
    v[t] = (__bf16)coeffs[(o * 64 + i) * 65 + b];
  }
  *(bf16x8*)(Bp + (size_t)frag * 512 + lane * 8) = v;

  if (blockIdx.x == 0 && threadIdx.x < 64) {
    int oo = threadIdx.x;
    float s = bias[oo];
    #pragma unroll 4
    for (int ii = 0; ii < 64; ++ii) s += coeffs[(oo * 64 + ii) * 65 + 0];
    bias2[oo] = s;
  }
}

// ---------------------------------------------------------------------------
// Staging: 256 threads DMA one 16 KB mode-tile (4 x 16B per thread, stride
// 4 KB).  Per chunk: LDS dest = wave-uniform base + lane*16 (HW rule).
// ---------------------------------------------------------------------------
__device__ __forceinline__ void stage_mode(const __bf16* __restrict__ Bp,
                                           __bf16* dst, int m, int tid) {
  const char* g = (const char*)Bp + (size_t)m * 16384 + tid * 16;
  char* l = (char*)dst + tid * 16;
  #pragma unroll
  for (int r = 0; r < 4; ++r) {
    __builtin_amdgcn_global_load_lds(
        (const __attribute__((address_space(1))) void*)(g + r * 4096),
        (__attribute__((address_space(3))) void*)(l + r * 4096), 16, 0, 0);
  }
}

// ---------------------------------------------------------------------------
// One mode (freq f = tile+1), one i-half: per kcr build the A-frag by
// recomputing sin/cos: r = f*ax (revolutions), fract, v_sin/v_cos.
// Then 8 ds_read_b128 + 8 MFMA.  Packing = scalar (__bf16) casts
// (R1-verified numerics; NOT v_cvt_pk_bf16_f32 per R5 failure).
// ---------------------------------------------------------------------------
__device__ __forceinline__ void mode_compute(const __bf16* buf, int lane,
    int h, const float* ax, float mf, f32x16* acc) {
  #pragma unroll
  for (int kcr = 0; kcr < 4; ++kcr) {
    bf16x8 af;
    #pragma unroll
    for (int e = 0; e < 4; ++e) {
      float r  = mf * ax[kcr * 4 + e];
      float rr = __builtin_amdgcn_fractf(r);        // [0,1) revolutions
      af[2 * e]     = (__bf16)__builtin_amdgcn_sinf(rr);  // sin(2*pi*rr)
      af[2 * e + 1] = (__bf16)__builtin_amdgcn_cosf(rr);  // cos(2*pi*rr)
    }
    int kc = 4 * h + kcr;
    #pragma unroll
    for (int c2 = 0; c2 < 2; ++c2) {
      bf16x8 bfv = *(const bf16x8*)(buf + (kc * 2 + c2) * 512 + lane * 8);
      acc[c2] = __builtin_amdgcn_mfma_f32_32x32x16_bf16(af, bfv, acc[c2],
                                                        0, 0, 0);
    }
  }
}

// ---------------------------------------------------------------------------
// Main kernel: 256 threads = 4 waves = 2 row-tiles x 2 i-halves;
// block = 64 rows x 64 cols; grid = 1024 (4 blocks/CU, 16 waves/CU,
// 4 waves/SIMD from 4 independent blocks).
// wave w: row-tile rt = w>>1, i-half h = w&1 (i in [32h, 32h+32)).
// Epilogue: h=1 waves write partial acc to LDS (2 lanes/bank = free),
// barrier, h=0 waves add + store.
// ---------------------------------------------------------------------------
__global__ __launch_bounds__(256, 4) void fkan_main(
    const float* __restrict__ x, const __bf16* __restrict__ Bp,
    const float* __restrict__ bias2, float* __restrict__ out) {
  __shared__ __bf16 Bs[2][8192];   // 2 x 16 KB double buffer; Bs[0] reused
                                   // as float[4096] (16 KB) for reduction

  int tid  = threadIdx.x;
  int wave = tid >> 6;             // 0..3
  int rt   = wave >> 1;            // row-tile 0..1
  int h    = wave & 1;             // i-half
  int lane = tid & 63;
  int kq   = lane >> 5;
  int cl   = lane & 31;
  int row  = blockIdx.x * 64 + rt * 32 + cl;

  // --- init: ax = x/2 (revolution step) for the lane's 16 (row,i) ----------
  // p = kcr*4 + e  ->  i = 32h + kcr*8 + kq*4 + e
  float ax[16];
  const float* xrow = x + (size_t)row * 64 + h * 32 + kq * 4;
  #pragma unroll
  for (int kcr = 0; kcr < 4; ++kcr) {
    f32x4 v = *(const f32x4*)(xrow + kcr * 8);
    #pragma unroll
    for (int e = 0; e < 4; ++e) ax[kcr * 4 + e] = 0.5f * v[e];
  }

  f32x16 acc[2];
  #pragma unroll
  for (int c2 = 0; c2 < 2; ++c2)
    #pragma unroll
    for (int r = 0; r < 16; ++r) acc[c2][r] = 0.f;

  // --- prologue: stage mode 0 ---------------------------------------------
  stage_mode(Bp, &Bs[0][0], 0, tid);
  __syncthreads();

  // --- main loop: modes 0..29 (R1's verified skeleton) --------------------
  #pragma unroll 1
  for (int m = 0; m < 30; m += 2) {
    stage_mode(Bp, &Bs[1][0], m + 1, tid);
    mode_compute(&Bs[0][0], lane, h, ax, (float)(m + 1), acc);   // tile m
    __syncthreads();

    stage_mode(Bp, &Bs[0][0], m + 2, tid);
    mode_compute(&Bs[1][0], lane, h, ax, (float)(m + 2), acc);   // tile m+1
    __syncthreads();
  }

  // --- tail: tiles 30, 31 --------------------------------------------------
  stage_mode(Bp, &Bs[1][0], 31, tid);
  mode_compute(&Bs[0][0], lane, h, ax, 31.0f, acc);              // tile 30
  __syncthreads();
  mode_compute(&Bs[1][0], lane, h, ax, 32.0f, acc);              // tile 31
  __syncthreads();   // all B-tile reads retired; Bs[0] reusable

  // --- cross-half reduction through LDS -----------------------------------
  // red[rt*2048 + r*64 + lane]: bank = lane%32 -> 2 lanes/bank (free).
  float* red = (float*)&Bs[0][0];
  if (h == 1) {
    #pragma unroll
    for (int r = 0; r < 32; ++r)
      red[rt * 2048 + r * 64 + lane] = acc[r >> 4][r & 15];
  }
  __syncthreads();

  if (h == 0) {
    #pragma unroll
    for (int r = 0; r < 32; ++r)
      acc[r >> 4][r & 15] += red[rt * 2048 + r * 64 + lane];

    // epilogue: C/D layout col=lane&31, row=(r&3)+8*(r>>2)+4*(lane>>5)
    float* orow = out + (size_t)(blockIdx.x * 64 + rt * 32) * 64;
    #pragma unroll
    for (int c2 = 0; c2 < 2; ++c2) {
      float b2 = bias2[c2 * 32 + cl];
      #pragma unroll
      for (int r = 0; r < 16; ++r) {
        int ro = (r & 3) + 8 * (r >> 2) + 4 * kq;
        orow[(size_t)ro * 64 + c2 * 32 + cl] = acc[c2][r] + b2;
      }
    }
  }
}

extern "C" void kernel_launch(void* const* d_in, const int* in_sizes, int n_in,
                              void* d_out, int out_size, void* d_ws, size_t ws_size,
                              hipStream_t stream) {
  const float* x      = (const float*)d_in[0];   // [65536, 64]
  const float* coeffs = (const float*)d_in[1];   // [64, 64, 65]
  const float* bias   = (const float*)d_in[2];   // [64]
  float* out = (float*)d_out;

  __bf16* Bp   = (__bf16*)d_ws;                  // 512 KB
  float* bias2 = (float*)((char*)d_ws + 512 * 1024);

  int n_rows = in_sizes[0] / 64;                 // 65536

  fkan_repack<<<128, 256, 0, stream>>>(coeffs, bias, Bp, bias2);
  fkan_main<<<n_rows / 64, 256, 0, stream>>>(x, Bp, bias2, out);
}